// Round 5
// baseline (271.669 us; speedup 1.0000x reference)
//
#include <hip/hip_runtime.h>
#include <cstdint>
#include <cstddef>

// MultiHeadAttention: B=2,S=2048,D_MODEL=1024,N_HEAD=16, "buggy" reshape:
// head h of batch b is the contiguous block X[b, h*128:(h+1)*128, :] viewed (2048,64).
// R5: attn split-K (chunks of <=8 BK=128 iters, f16 unnormalized-O partials + merge
// kernel) -> grid 2048, ~3 staggered blocks/CU; gemm_out retiled 128x64 (grid 512).

typedef _Float16 f16;
typedef _Float16 f16x8 __attribute__((ext_vector_type(8)));
typedef float f32x4 __attribute__((ext_vector_type(4)));

#define NB 2
#define NS 2048
#define NDM 1024
#define NHEAD 16

// async global->LDS, 16B per lane; LDS dest = wave-uniform base + lane*16
__device__ __forceinline__ void gload16(void* lds, const void* g) {
    __builtin_amdgcn_global_load_lds(
        (__attribute__((address_space(1))) void*)g,
        (__attribute__((address_space(3))) void*)lds, 16, 0, 0);
}

__device__ __forceinline__ float fast_exp2(float x) {
#if __has_builtin(__builtin_amdgcn_exp2f)
    return __builtin_amdgcn_exp2f(x);
#else
    return __expf(x * 0.69314718055994531f);
#endif
}

// ---------------- cast fp32 -> fp16 (q,k,v) ----------------
__global__ __launch_bounds__(256) void cast3_kernel(
    const float* __restrict__ s0, const float* __restrict__ s1, const float* __restrict__ s2,
    f16* __restrict__ d0, f16* __restrict__ d1, f16* __restrict__ d2, int nvec)
{
    const float* s = blockIdx.z == 0 ? s0 : (blockIdx.z == 1 ? s1 : s2);
    f16* d        = blockIdx.z == 0 ? d0 : (blockIdx.z == 1 ? d1 : d2);
    int vi = blockIdx.x * 256 + threadIdx.x;
    if (vi >= nvec) return;
    const float4* sp = (const float4*)s;
    float4 a = sp[vi * 2 + 0];
    float4 b = sp[vi * 2 + 1];
    f16x8 h;
    h[0] = (f16)a.x; h[1] = (f16)a.y; h[2] = (f16)a.z; h[3] = (f16)a.w;
    h[4] = (f16)b.x; h[5] = (f16)b.y; h[6] = (f16)b.z; h[7] = (f16)b.w;
    *(f16x8*)(d + (size_t)vi * 8) = h;
}

// ---------------- transpose + cast the 1024x1024 weight mats ----------------
__global__ __launch_bounds__(256) void tcast4_kernel(
    const float* __restrict__ w0, const float* __restrict__ w1,
    const float* __restrict__ w2, const float* __restrict__ w3,
    f16* __restrict__ t0, f16* __restrict__ t1, f16* __restrict__ t2, f16* __restrict__ t3)
{
    const int n = 1024;
    const float* W; f16* T;
    switch (blockIdx.z) {
        case 0: W = w0; T = t0; break;
        case 1: W = w1; T = t1; break;
        case 2: W = w2; T = t2; break;
        default: W = w3; T = t3; break;
    }
    __shared__ float tile[32][33];
    int tx = threadIdx.x, ty = threadIdx.y;     // block (32,8)
    int c0 = blockIdx.x * 32, r0 = blockIdx.y * 32;
    #pragma unroll
    for (int i = 0; i < 32; i += 8)
        tile[ty + i][tx] = W[(size_t)(r0 + ty + i) * n + c0 + tx];
    __syncthreads();
    #pragma unroll
    for (int i = 0; i < 32; i += 8)
        T[(size_t)(c0 + ty + i) * n + r0 + tx] = (f16)tile[tx][ty + i];
}

// ---------------- GEMM  C(MxN) = A(MxK) * Bt(NxK)^T, 128x128 tile, BK=64 ----------------
// global_load_lds staging, XOR-swizzled chunks: LDS[row][c*8] holds global chunk c^(row&7).
template <typename CT>
__device__ __forceinline__ void gemm_abt_body(
    const f16* __restrict__ A, const f16* __restrict__ Bt, CT* __restrict__ C,
    int M, int N, int K, int bx, int by, float cscale)
{
    __shared__ f16 As[128][64];
    __shared__ f16 Bs[128][64];
    const int tid  = threadIdx.x;
    const int lane = tid & 63, wave = tid >> 6;
    const int quad = lane >> 4, ln = lane & 15;
    const int wm = wave >> 1, wn = wave & 1;
    const int m0 = by * 128, n0 = bx * 128;
    const int r8 = lane >> 3, c8 = lane & 7;
    const int swz = ((c8 ^ r8) * 8);           // global chunk this lane fetches

    f32x4 acc[4][4] = {};
    for (int k0 = 0; k0 < K; k0 += 64) {
        __syncthreads();
        #pragma unroll
        for (int i = 0; i < 4; i++) {
            int blk = wave * 4 + i;            // 8-row group, 0..15
            int row = blk * 8 + r8;
            gload16(&As[blk * 8][0], &A [(size_t)(m0 + row) * K + k0 + swz]);
            gload16(&Bs[blk * 8][0], &Bt[(size_t)(n0 + row) * K + k0 + swz]);
        }
        __syncthreads();
        #pragma unroll
        for (int kc = 0; kc < 2; kc++) {
            f16x8 af[4], bfr[4];
            #pragma unroll
            for (int mt = 0; mt < 4; mt++)
                af[mt] = *(const f16x8*)&As[wm * 64 + mt * 16 + ln][((kc * 4 + quad) ^ (ln & 7)) * 8];
            #pragma unroll
            for (int nt = 0; nt < 4; nt++)
                bfr[nt] = *(const f16x8*)&Bs[wn * 64 + nt * 16 + ln][((kc * 4 + quad) ^ (ln & 7)) * 8];
            #pragma unroll
            for (int mt = 0; mt < 4; mt++)
                #pragma unroll
                for (int nt = 0; nt < 4; nt++)
                    acc[mt][nt] = __builtin_amdgcn_mfma_f32_16x16x32_f16(af[mt], bfr[nt], acc[mt][nt], 0, 0, 0);
        }
    }
    #pragma unroll
    for (int mt = 0; mt < 4; mt++)
        #pragma unroll
        for (int nt = 0; nt < 4; nt++)
            #pragma unroll
            for (int r = 0; r < 4; r++) {
                int row = m0 + wm * 64 + mt * 16 + quad * 4 + r;
                int col = n0 + wn * 64 + nt * 16 + ln;
                C[(size_t)row * N + col] = (CT)(acc[mt][nt][r] * cscale);
            }
}

__global__ __launch_bounds__(256) void gemm3_kernel(
    const f16* __restrict__ a0, const f16* __restrict__ a1, const f16* __restrict__ a2,
    const f16* __restrict__ b0, const f16* __restrict__ b1, const f16* __restrict__ b2,
    f16* __restrict__ c0, f16* __restrict__ c1, f16* __restrict__ c2, int M, int N, int K)
{
    const f16 *A, *Bt; f16* C; float sc;
    switch (blockIdx.z) {
        case 0: A = a0; Bt = b0; C = c0; sc = 1.4426950408889634f; break;  // Q * log2(e)
        case 1: A = a1; Bt = b1; C = c1; sc = 1.0f; break;
        default: A = a2; Bt = b2; C = c2; sc = 1.0f; break;
    }
    gemm_abt_body<f16>(A, Bt, C, M, N, K, blockIdx.x, blockIdx.y, sc);
}

// ---------------- out GEMM: 128x64 tiles -> grid 512 = 2 blocks/CU ----------------
__global__ __launch_bounds__(256) void gemm_out_kernel(
    const f16* __restrict__ A, const f16* __restrict__ Bt, float* __restrict__ C,
    int M, int N, int K)
{
    __shared__ f16 As[128][64];   // 16 KB
    __shared__ f16 Bs[64][64];    //  8 KB
    const int tid  = threadIdx.x;
    const int lane = tid & 63, wave = tid >> 6;
    const int quad = lane >> 4, ln = lane & 15;
    const int m0 = blockIdx.y * 128, n0 = blockIdx.x * 64;
    const int r8 = lane >> 3, c8 = lane & 7;
    const int swz = ((c8 ^ r8) * 8);

    f32x4 acc[2][4] = {};
    for (int k0 = 0; k0 < K; k0 += 64) {
        __syncthreads();
        #pragma unroll
        for (int i = 0; i < 4; i++) {
            int blk = wave * 4 + i;            // 0..15
            gload16(&As[blk * 8][0], &A[(size_t)(m0 + blk * 8 + r8) * K + k0 + swz]);
        }
        #pragma unroll
        for (int i = 0; i < 2; i++) {
            int blk = wave * 2 + i;            // 0..7
            gload16(&Bs[blk * 8][0], &Bt[(size_t)(n0 + blk * 8 + r8) * K + k0 + swz]);
        }
        __syncthreads();
        #pragma unroll
        for (int kc = 0; kc < 2; kc++) {
            f16x8 af[2], bfr[4];
            #pragma unroll
            for (int mt = 0; mt < 2; mt++)
                af[mt] = *(const f16x8*)&As[wave * 32 + mt * 16 + ln][((kc * 4 + quad) ^ (ln & 7)) * 8];
            #pragma unroll
            for (int nt = 0; nt < 4; nt++)
                bfr[nt] = *(const f16x8*)&Bs[nt * 16 + ln][((kc * 4 + quad) ^ (ln & 7)) * 8];
            #pragma unroll
            for (int mt = 0; mt < 2; mt++)
                #pragma unroll
                for (int nt = 0; nt < 4; nt++)
                    acc[mt][nt] = __builtin_amdgcn_mfma_f32_16x16x32_f16(af[mt], bfr[nt], acc[mt][nt], 0, 0, 0);
        }
    }
    #pragma unroll
    for (int mt = 0; mt < 2; mt++)
        #pragma unroll
        for (int nt = 0; nt < 4; nt++)
            #pragma unroll
            for (int r = 0; r < 4; r++) {
                int row = m0 + wave * 32 + mt * 16 + quad * 4 + r;
                int col = n0 + nt * 16 + ln;
                C[(size_t)row * N + col] = acc[mt][nt][r];
            }
}

// ---------------- global V transpose: per head (2048x64) -> (64x2048) ----------------
__global__ __launch_bounds__(256) void vtrans_kernel(
    const f16* __restrict__ Vp, f16* __restrict__ Vt)
{
    const int kt = blockIdx.x;   // key tile of 64
    const int h  = blockIdx.y;
    const int b  = blockIdx.z;
    const f16* src = Vp + (size_t)b * (NS * NDM) + (size_t)h * (128 * NDM);  // (2048,64)
    f16* dst = Vt + (size_t)(b * NHEAD + h) * (64 * 2048);

    __shared__ f16 Ls[64][64];
    const int tid = threadIdx.x;
    #pragma unroll
    for (int i = 0; i < 2; i++) {
        int vi = tid + i * 256;
        int key = vi >> 3, c = vi & 7;
        int cs = c ^ ((key >> 3) & 7);
        *(uint4*)&Ls[key][cs * 8] = *(const uint4*)&src[(size_t)(kt * 64 + key) * 64 + c * 8];
    }
    __syncthreads();
    #pragma unroll
    for (int i = 0; i < 2; i++) {
        int vi = tid + i * 256;
        int d2 = vi >> 3, kc = vi & 7;
        int cs = (d2 >> 3) ^ kc;
        f16 tmp[8];
        #pragma unroll
        for (int j = 0; j < 8; j++)
            tmp[j] = Ls[kc * 8 + j][cs * 8 + (d2 & 7)];
        *(uint4*)&dst[(size_t)d2 * 2048 + kt * 64 + kc * 8] = *(uint4*)tmp;
    }
}

// ---------------- flash attention v5: split-K ----------------
// Block (qt, chunk, z=b*16+h): processes key-chunk of <=8 BK=128 iters for q-tile qt.
// Writes unnormalized O (f16) + m,l (f32) partials; merge kernel combines <=2 chunks.
__global__ __launch_bounds__(256) void attn_kernel(
    const f16* __restrict__ Qp, const f16* __restrict__ Kp, const f16* __restrict__ Vt,
    f16* __restrict__ Opart, float* __restrict__ Mpart, float* __restrict__ Lpart)
{
    const int qt = blockIdx.x;       // 0..31
    const int chunk = blockIdx.y;    // 0..1
    const int z = blockIdx.z;        // b*16+h
    const int nkt = (qt + 2) >> 1;   // BK=128 tiles covering (qt+1)*64 keys
    const int nch = (nkt + 7) >> 3;  // 1 or 2 chunks of <=8 tiles
    if (chunk >= nch) return;        // empty block, exit immediately
    const int h = z & 15, b = z >> 4;

    const size_t hb = (size_t)b * (NS * NDM) + (size_t)h * (128 * NDM);
    const f16* Qh = Qp + hb;                                    // (2048,64), pre-scaled log2e
    const f16* Kh = Kp + hb;                                    // (2048,64)
    const f16* Vh = Vt + (size_t)z * (64 * 2048);               // (64,2048) transposed

    __shared__ f16 PQ[64][136];      // 17 KB union: Q tile (cols 0..63) -> per-wave P
    __shared__ f16 Ks[128][64];      // 16 KB (XOR swizzle row&7)
    __shared__ f16 Vs[64][128];      // 16 KB Vs[d2][key] (XOR swizzle row&15)

    const int tid  = threadIdx.x;
    const int lane = tid & 63, wave = tid >> 6;
    const int quad = lane >> 4, ln = lane & 15;
    const int r8 = lane >> 3, c8 = lane & 7;      // K staging coords
    const int r4 = lane >> 4, c16 = lane & 15;    // V staging coords

    // stage Q tile into the union buffer
    #pragma unroll
    for (int i = 0; i < 2; i++) {
        int vi = tid + i * 256;
        int row = vi >> 3, kk = (vi & 7) * 8;
        *(uint4*)&PQ[row][kk] = *(const uint4*)&Qh[(size_t)(qt * 64 + row) * 64 + kk];
    }
    __syncthreads();
    f16x8 qf[2];
    #pragma unroll
    for (int kc = 0; kc < 2; kc++)
        qf[kc] = *(const f16x8*)&PQ[wave * 16 + ln][kc * 32 + quad * 8];

    float m_i[4], l_i[4];
    #pragma unroll
    for (int r = 0; r < 4; r++) { m_i[r] = -3e30f; l_i[r] = 0.f; }
    f32x4 o[4] = {};

    const int kt0 = chunk * 8;
    const int kt1 = (kt0 + 8 < nkt) ? (kt0 + 8) : nkt;
    for (int kt = kt0; kt < kt1; kt++) {
        __syncthreads();   // previous iteration's Ks/Vs readers done (also guards qf reads)
        #pragma unroll
        for (int i = 0; i < 4; i++) {
            int blk = wave * 4 + i;                 // 0..15
            int krow = blk * 8 + r8;                // 0..127
            gload16(&Ks[blk * 8][0], &Kh[(size_t)(kt * 128 + krow) * 64 + ((c8 ^ r8) * 8)]);
            int vrow = blk * 4 + r4;                // 0..63
            gload16(&Vs[blk * 4][0], &Vh[(size_t)vrow * 2048 + kt * 128 + ((c16 ^ (vrow & 15)) * 8)]);
        }
        __syncthreads();

        // S2 = (Q*log2e) K^T : wave's 16 rows x 128 keys
        f32x4 sf[8] = {};
        #pragma unroll
        for (int kc = 0; kc < 2; kc++)
            #pragma unroll
            for (int ct = 0; ct < 8; ct++) {
                int krow = ct * 16 + ln;
                f16x8 kf = *(const f16x8*)&Ks[krow][((kc * 4 + quad) ^ (ln & 7)) * 8];
                sf[ct] = __builtin_amdgcn_mfma_f32_16x16x32_f16(qf[kc], kf, sf[ct], 0, 0, 0);
            }

        if (kt == nkt - 1) {   // global diagonal tile: causal mask (+ tail over-span)
            #pragma unroll
            for (int ct = 0; ct < 8; ct++) {
                int jg = kt * 128 + ct * 16 + ln;
                #pragma unroll
                for (int r = 0; r < 4; r++) {
                    int ig = qt * 64 + wave * 16 + quad * 4 + r;
                    if (jg > ig) sf[ct][r] = -3e30f;
                }
            }
        }

        // online softmax in exp2 domain: 4 rows, each 16 lanes x 8 regs
        float alpha[4];
        #pragma unroll
        for (int r = 0; r < 4; r++) {
            float tm = sf[0][r];
            #pragma unroll
            for (int ct = 1; ct < 8; ct++) tm = fmaxf(tm, sf[ct][r]);
            #pragma unroll
            for (int off = 1; off < 16; off <<= 1) tm = fmaxf(tm, __shfl_xor(tm, off, 64));
            float mnew = fmaxf(m_i[r], tm);
            float a = fast_exp2(m_i[r] - mnew);
            float rs = 0.f;
            #pragma unroll
            for (int ct = 0; ct < 8; ct++) {
                float pv = fast_exp2(sf[ct][r] - mnew);
                sf[ct][r] = pv; rs += pv;
            }
            #pragma unroll
            for (int off = 1; off < 16; off <<= 1) rs += __shfl_xor(rs, off, 64);
            m_i[r] = mnew; l_i[r] = l_i[r] * a + rs; alpha[r] = a;
        }
        #pragma unroll
        for (int vt = 0; vt < 4; vt++)
            #pragma unroll
            for (int r = 0; r < 4; r++) o[vt][r] *= alpha[r];

        // P: C-layout -> per-wave-private rows of PQ -> A-layout (no barrier)
        #pragma unroll
        for (int ct = 0; ct < 8; ct++)
            #pragma unroll
            for (int r = 0; r < 4; r++)
                PQ[wave * 16 + quad * 4 + r][ct * 16 + ln] = (f16)sf[ct][r];

        // O += P V  (A = P[q][key] 16x128, B = V^T[d2][key])
        #pragma unroll
        for (int kc = 0; kc < 4; kc++) {
            f16x8 pa = *(const f16x8*)&PQ[wave * 16 + ln][kc * 32 + quad * 8];
            #pragma unroll
            for (int vt = 0; vt < 4; vt++) {
                int vrow = vt * 16 + ln;
                f16x8 vb = *(const f16x8*)&Vs[vrow][(((kc * 4 + quad) ^ ln) & 15) * 8];
                o[vt] = __builtin_amdgcn_mfma_f32_16x16x32_f16(pa, vb, o[vt], 0, 0, 0);
            }
        }
    }

    // epilogue: write UNNORMALIZED partial O (f16) + m,l (f32)
    const int pid = (z * 32 + qt) * 2 + chunk;
    f16* Op = Opart + (size_t)pid * 4096;
    #pragma unroll
    for (int r = 0; r < 4; r++) {
        int s2l = wave * 16 + quad * 4 + r;
        #pragma unroll
        for (int vt = 0; vt < 4; vt++)
            Op[s2l * 64 + vt * 16 + ln] = (f16)o[vt][r];
        if (ln == 0) {
            Mpart[pid * 64 + s2l] = m_i[r];
            Lpart[pid * 64 + s2l] = l_i[r];
        }
    }
}

// ---------------- split-K merge: combine <=2 chunks, normalize, write att ----------------
__global__ __launch_bounds__(256) void attn_merge_kernel(
    const f16* __restrict__ Opart, const float* __restrict__ Mpart, const float* __restrict__ Lpart,
    f16* __restrict__ att)
{
    const int qt = blockIdx.x, z = blockIdx.y;
    const int h = z & 15, b = z >> 4;
    const int nkt = (qt + 2) >> 1;
    const int nch = (nkt + 7) >> 3;
    const int tid = threadIdx.x;
    const int r = tid >> 2, cg = (tid & 3) * 16;
    const int pid0 = (z * 32 + qt) * 2;
    const f16* O0 = Opart + (size_t)pid0 * 4096 + r * 64 + cg;

    float m0 = Mpart[pid0 * 64 + r], l0 = Lpart[pid0 * 64 + r];
    float w0 = 1.f, w1 = 0.f, inv;
    if (nch == 2) {
        float m1 = Mpart[(pid0 + 1) * 64 + r], l1 = Lpart[(pid0 + 1) * 64 + r];
        float m = fmaxf(m0, m1);
        w0 = fast_exp2(m0 - m); w1 = fast_exp2(m1 - m);
        inv = 1.f / (w0 * l0 + w1 * l1);
    } else {
        inv = 1.f / l0;
    }

    f16x8 a0 = *(const f16x8*)(O0);
    f16x8 a1 = *(const f16x8*)(O0 + 8);
    f16x8 outv0, outv1;
    if (nch == 2) {
        const f16* O1 = O0 + 4096;
        f16x8 b0v = *(const f16x8*)(O1);
        f16x8 b1v = *(const f16x8*)(O1 + 8);
        #pragma unroll
        for (int j = 0; j < 8; j++) {
            outv0[j] = (f16)((w0 * (float)a0[j] + w1 * (float)b0v[j]) * inv);
            outv1[j] = (f16)((w0 * (float)a1[j] + w1 * (float)b1v[j]) * inv);
        }
    } else {
        #pragma unroll
        for (int j = 0; j < 8; j++) {
            outv0[j] = (f16)((float)a0[j] * inv);
            outv1[j] = (f16)((float)a1[j] * inv);
        }
    }
    f16* dst = att + ((size_t)(b * NS) + qt * 64 + r) * NDM + h * 64 + cg;
    *(f16x8*)(dst) = outv0;
    *(f16x8*)(dst + 8) = outv1;
}

extern "C" void kernel_launch(void* const* d_in, const int* in_sizes, int n_in,
                              void* d_out, int out_size, void* d_ws, size_t ws_size,
                              hipStream_t stream)
{
    const float* q  = (const float*)d_in[0];
    const float* k  = (const float*)d_in[1];
    const float* v  = (const float*)d_in[2];
    const float* Wq = (const float*)d_in[3];
    const float* Wk = (const float*)d_in[4];
    const float* Wv = (const float*)d_in[5];
    const float* Wp = (const float*)d_in[6];
    float* out = (float*)d_out;

    char* ws = (char*)d_ws;
    const size_t MB = 1024 * 1024;
    f16* qb   = (f16*)(ws + 0 * MB);    // dead after gemm3 -> reused as Opart
    f16* kb   = (f16*)(ws + 8 * MB);
    f16* vb   = (f16*)(ws + 16 * MB);   // reused as Vtg after gemm3 consumes it
    f16* Wqt  = (f16*)(ws + 24 * MB);
    f16* Wkt  = (f16*)(ws + 26 * MB);
    f16* Wvt  = (f16*)(ws + 28 * MB);
    f16* Wpt  = (f16*)(ws + 30 * MB);
    f16* Qp   = (f16*)(ws + 32 * MB);
    f16* Kp   = (f16*)(ws + 40 * MB);
    f16* Vp   = (f16*)(ws + 48 * MB);   // dead after vtrans -> reused as M/Lpart
    f16* attb = (f16*)(ws + 56 * MB);
    f16* Vtg  = vb;                     // (2,16,64,2048) transposed V heads

    f16*   Opart = qb;                  // 2048 slots x 4096 f16 = 16 MB  [0,16MB)
    float* Mpart = (float*)(ws + 48 * MB);          // 2048 x 64 f32 = 512 KB
    float* Lpart = (float*)(ws + 49 * MB);          // 512 KB

    const int M = NB * NS;      // 4096
    const int N = NDM;          // 1024
    const int K = NDM;          // 1024

    cast3_kernel<<<dim3(2048, 1, 3), 256, 0, stream>>>(q, k, v, qb, kb, vb, (M * NDM) / 8);
    tcast4_kernel<<<dim3(32, 32, 4), dim3(32, 8), 0, stream>>>(Wq, Wk, Wv, Wp, Wqt, Wkt, Wvt, Wpt);
    gemm3_kernel<<<dim3(N / 128, M / 128, 3), 256, 0, stream>>>(qb, kb, vb, Wqt, Wkt, Wvt, Qp, Kp, Vp, M, N, K);
    vtrans_kernel<<<dim3(32, NHEAD, NB), 256, 0, stream>>>(Vp, Vtg);
    attn_kernel<<<dim3(32, 2, 32), 256, 0, stream>>>(Qp, Kp, Vtg, Opart, Mpart, Lpart);
    attn_merge_kernel<<<dim3(32, 32), 256, 0, stream>>>(Opart, Mpart, Lpart, attb);
    gemm_out_kernel<<<dim3(N / 64, M / 128), 256, 0, stream>>>(attb, Wpt, out, M, N, K);
}

// Round 6
// 239.673 us; speedup vs baseline: 1.1335x; 1.1335x over previous
//
#include <hip/hip_runtime.h>
#include <cstdint>
#include <cstddef>

// MultiHeadAttention: B=2,S=2048,D_MODEL=1024,N_HEAD=16, "buggy" reshape:
// head h of batch b is the contiguous block X[b, h*128:(h+1)*128, :] viewed (2048,64).
// R6: split-K reverted (R5 post-mortem: per-block overhead x3 blocks beat the occupancy
// gain). Attn = R4 balanced-pair structure + l-via-MFMA ones-trick (kills the row-sum
// shuffle reduce). cast+tcast fused into one prep kernel. gemm_out 128x64 (2 blk/CU).

typedef _Float16 f16;
typedef _Float16 f16x8 __attribute__((ext_vector_type(8)));
typedef float f32x4 __attribute__((ext_vector_type(4)));

#define NB 2
#define NS 2048
#define NDM 1024
#define NHEAD 16

// async global->LDS, 16B per lane; LDS dest = wave-uniform base + lane*16
__device__ __forceinline__ void gload16(void* lds, const void* g) {
    __builtin_amdgcn_global_load_lds(
        (__attribute__((address_space(1))) void*)g,
        (__attribute__((address_space(3))) void*)lds, 16, 0, 0);
}

__device__ __forceinline__ float fast_exp2(float x) {
#if __has_builtin(__builtin_amdgcn_exp2f)
    return __builtin_amdgcn_exp2f(x);
#else
    return __expf(x * 0.69314718055994531f);
#endif
}

// ---------------- fused prep: cast q/k/v -> f16, transpose+cast 4 weight mats ----------------
// blocks [0,6144): cast (3 arrays x 2048 blocks, 8 f32->f16 per thread)
// blocks [6144,10240): transpose (4 mats x 1024 32x32-tiles)
__global__ __launch_bounds__(256) void prep_kernel(
    const float* __restrict__ q, const float* __restrict__ k, const float* __restrict__ v,
    f16* __restrict__ qb, f16* __restrict__ kb, f16* __restrict__ vb,
    const float* __restrict__ w0, const float* __restrict__ w1,
    const float* __restrict__ w2, const float* __restrict__ w3,
    f16* __restrict__ t0, f16* __restrict__ t1, f16* __restrict__ t2, f16* __restrict__ t3)
{
    __shared__ float tile[32][33];
    const int bx = blockIdx.x, tid = threadIdx.x;
    if (bx < 6144) {
        const int arr = bx >> 11;                 // 0..2
        const float* s = arr == 0 ? q : (arr == 1 ? k : v);
        f16* d        = arr == 0 ? qb : (arr == 1 ? kb : vb);
        int vi = (bx & 2047) * 256 + tid;
        const float4* sp = (const float4*)s;
        float4 a = sp[vi * 2 + 0];
        float4 b = sp[vi * 2 + 1];
        f16x8 h;
        h[0] = (f16)a.x; h[1] = (f16)a.y; h[2] = (f16)a.z; h[3] = (f16)a.w;
        h[4] = (f16)b.x; h[5] = (f16)b.y; h[6] = (f16)b.z; h[7] = (f16)b.w;
        *(f16x8*)(d + (size_t)vi * 8) = h;
    } else {
        const int t = bx - 6144;
        const int mat = t >> 10, tl = t & 1023;
        const float* W; f16* T;
        switch (mat) {
            case 0: W = w0; T = t0; break;
            case 1: W = w1; T = t1; break;
            case 2: W = w2; T = t2; break;
            default: W = w3; T = t3; break;
        }
        const int n = 1024;
        const int tx = tid & 31, ty = tid >> 5;   // (32,8)
        const int c0 = (tl & 31) * 32, r0 = (tl >> 5) * 32;
        #pragma unroll
        for (int i = 0; i < 32; i += 8)
            tile[ty + i][tx] = W[(size_t)(r0 + ty + i) * n + c0 + tx];
        __syncthreads();
        #pragma unroll
        for (int i = 0; i < 32; i += 8)
            T[(size_t)(c0 + ty + i) * n + r0 + tx] = (f16)tile[tx][ty + i];
    }
}

// ---------------- GEMM  C(MxN) = A(MxK) * Bt(NxK)^T, 128x128 tile, BK=64 ----------------
// global_load_lds staging, XOR-swizzled chunks: LDS[row][c*8] holds global chunk c^(row&7).
template <typename CT>
__device__ __forceinline__ void gemm_abt_body(
    const f16* __restrict__ A, const f16* __restrict__ Bt, CT* __restrict__ C,
    int M, int N, int K, int bx, int by, float cscale)
{
    __shared__ f16 As[128][64];
    __shared__ f16 Bs[128][64];
    const int tid  = threadIdx.x;
    const int lane = tid & 63, wave = tid >> 6;
    const int quad = lane >> 4, ln = lane & 15;
    const int wm = wave >> 1, wn = wave & 1;
    const int m0 = by * 128, n0 = bx * 128;
    const int r8 = lane >> 3, c8 = lane & 7;
    const int swz = ((c8 ^ r8) * 8);           // global chunk this lane fetches

    f32x4 acc[4][4] = {};
    for (int k0 = 0; k0 < K; k0 += 64) {
        __syncthreads();
        #pragma unroll
        for (int i = 0; i < 4; i++) {
            int blk = wave * 4 + i;            // 8-row group, 0..15
            int row = blk * 8 + r8;
            gload16(&As[blk * 8][0], &A [(size_t)(m0 + row) * K + k0 + swz]);
            gload16(&Bs[blk * 8][0], &Bt[(size_t)(n0 + row) * K + k0 + swz]);
        }
        __syncthreads();
        #pragma unroll
        for (int kc = 0; kc < 2; kc++) {
            f16x8 af[4], bfr[4];
            #pragma unroll
            for (int mt = 0; mt < 4; mt++)
                af[mt] = *(const f16x8*)&As[wm * 64 + mt * 16 + ln][((kc * 4 + quad) ^ (ln & 7)) * 8];
            #pragma unroll
            for (int nt = 0; nt < 4; nt++)
                bfr[nt] = *(const f16x8*)&Bs[wn * 64 + nt * 16 + ln][((kc * 4 + quad) ^ (ln & 7)) * 8];
            #pragma unroll
            for (int mt = 0; mt < 4; mt++)
                #pragma unroll
                for (int nt = 0; nt < 4; nt++)
                    acc[mt][nt] = __builtin_amdgcn_mfma_f32_16x16x32_f16(af[mt], bfr[nt], acc[mt][nt], 0, 0, 0);
        }
    }
    #pragma unroll
    for (int mt = 0; mt < 4; mt++)
        #pragma unroll
        for (int nt = 0; nt < 4; nt++)
            #pragma unroll
            for (int r = 0; r < 4; r++) {
                int row = m0 + wm * 64 + mt * 16 + quad * 4 + r;
                int col = n0 + wn * 64 + nt * 16 + ln;
                C[(size_t)row * N + col] = (CT)(acc[mt][nt][r] * cscale);
            }
}

__global__ __launch_bounds__(256) void gemm3_kernel(
    const f16* __restrict__ a0, const f16* __restrict__ a1, const f16* __restrict__ a2,
    const f16* __restrict__ b0, const f16* __restrict__ b1, const f16* __restrict__ b2,
    f16* __restrict__ c0, f16* __restrict__ c1, f16* __restrict__ c2, int M, int N, int K)
{
    const f16 *A, *Bt; f16* C; float sc;
    switch (blockIdx.z) {
        case 0: A = a0; Bt = b0; C = c0; sc = 1.4426950408889634f; break;  // Q * log2(e)
        case 1: A = a1; Bt = b1; C = c1; sc = 1.0f; break;
        default: A = a2; Bt = b2; C = c2; sc = 1.0f; break;
    }
    gemm_abt_body<f16>(A, Bt, C, M, N, K, blockIdx.x, blockIdx.y, sc);
}

// ---------------- out GEMM: 128x64 tiles -> grid 512 = 2 blocks/CU ----------------
__global__ __launch_bounds__(256) void gemm_out_kernel(
    const f16* __restrict__ A, const f16* __restrict__ Bt, float* __restrict__ C,
    int M, int N, int K)
{
    __shared__ f16 As[128][64];   // 16 KB
    __shared__ f16 Bs[64][64];    //  8 KB
    const int tid  = threadIdx.x;
    const int lane = tid & 63, wave = tid >> 6;
    const int quad = lane >> 4, ln = lane & 15;
    const int m0 = blockIdx.y * 128, n0 = blockIdx.x * 64;
    const int r8 = lane >> 3, c8 = lane & 7;
    const int swz = ((c8 ^ r8) * 8);

    f32x4 acc[2][4] = {};
    for (int k0 = 0; k0 < K; k0 += 64) {
        __syncthreads();
        #pragma unroll
        for (int i = 0; i < 4; i++) {
            int blk = wave * 4 + i;            // 0..15
            gload16(&As[blk * 8][0], &A[(size_t)(m0 + blk * 8 + r8) * K + k0 + swz]);
        }
        #pragma unroll
        for (int i = 0; i < 2; i++) {
            int blk = wave * 2 + i;            // 0..7
            gload16(&Bs[blk * 8][0], &Bt[(size_t)(n0 + blk * 8 + r8) * K + k0 + swz]);
        }
        __syncthreads();
        #pragma unroll
        for (int kc = 0; kc < 2; kc++) {
            f16x8 af[2], bfr[4];
            #pragma unroll
            for (int mt = 0; mt < 2; mt++)
                af[mt] = *(const f16x8*)&As[wave * 32 + mt * 16 + ln][((kc * 4 + quad) ^ (ln & 7)) * 8];
            #pragma unroll
            for (int nt = 0; nt < 4; nt++)
                bfr[nt] = *(const f16x8*)&Bs[nt * 16 + ln][((kc * 4 + quad) ^ (ln & 7)) * 8];
            #pragma unroll
            for (int mt = 0; mt < 2; mt++)
                #pragma unroll
                for (int nt = 0; nt < 4; nt++)
                    acc[mt][nt] = __builtin_amdgcn_mfma_f32_16x16x32_f16(af[mt], bfr[nt], acc[mt][nt], 0, 0, 0);
        }
    }
    #pragma unroll
    for (int mt = 0; mt < 2; mt++)
        #pragma unroll
        for (int nt = 0; nt < 4; nt++)
            #pragma unroll
            for (int r = 0; r < 4; r++) {
                int row = m0 + wave * 32 + mt * 16 + quad * 4 + r;
                int col = n0 + nt * 16 + ln;
                C[(size_t)row * N + col] = acc[mt][nt][r];
            }
}

// ---------------- global V transpose: per head (2048x64) -> (64x2048) ----------------
__global__ __launch_bounds__(256) void vtrans_kernel(
    const f16* __restrict__ Vp, f16* __restrict__ Vt)
{
    const int kt = blockIdx.x;   // key tile of 64
    const int h  = blockIdx.y;
    const int b  = blockIdx.z;
    const f16* src = Vp + (size_t)b * (NS * NDM) + (size_t)h * (128 * NDM);  // (2048,64)
    f16* dst = Vt + (size_t)(b * NHEAD + h) * (64 * 2048);

    __shared__ f16 Ls[64][64];
    const int tid = threadIdx.x;
    #pragma unroll
    for (int i = 0; i < 2; i++) {
        int vi = tid + i * 256;
        int key = vi >> 3, c = vi & 7;
        int cs = c ^ ((key >> 3) & 7);
        *(uint4*)&Ls[key][cs * 8] = *(const uint4*)&src[(size_t)(kt * 64 + key) * 64 + c * 8];
    }
    __syncthreads();
    #pragma unroll
    for (int i = 0; i < 2; i++) {
        int vi = tid + i * 256;
        int d2 = vi >> 3, kc = vi & 7;
        int cs = (d2 >> 3) ^ kc;
        f16 tmp[8];
        #pragma unroll
        for (int j = 0; j < 8; j++)
            tmp[j] = Ls[kc * 8 + j][cs * 8 + (d2 & 7)];
        *(uint4*)&dst[(size_t)d2 * 2048 + kt * 64 + kc * 8] = *(uint4*)tmp;
    }
}

// ---------------- flash attention v6 ----------------
// Block p handles q-tiles (31-p) then (p): exactly 17 BK=128 iterations each.
// LDS 49KB. Softmax in exp2 domain; l computed as a 5th PV output column via a
// constant all-ones B-frag MFMA (removes the row-sum shuffle reduce entirely).
__global__ __launch_bounds__(256) void attn_kernel(
    const f16* __restrict__ Qp, const f16* __restrict__ Kp, const f16* __restrict__ Vt,
    f16* __restrict__ att)
{
    const int p = blockIdx.x;    // 0..15 pair index
    const int h = blockIdx.y;
    const int b = blockIdx.z;
    const size_t hb = (size_t)b * (NS * NDM) + (size_t)h * (128 * NDM);
    const f16* Qh = Qp + hb;                                    // (2048,64), pre-scaled log2e
    const f16* Kh = Kp + hb;                                    // (2048,64)
    const f16* Vh = Vt + (size_t)(b * NHEAD + h) * (64 * 2048); // (64,2048) transposed

    __shared__ f16 PQ[64][136];      // 17 KB union: Q tile (cols 0..63) -> per-wave P
    __shared__ f16 Ks[128][64];      // 16 KB (XOR swizzle row&7)
    __shared__ f16 Vs[64][128];      // 16 KB Vs[d2][key] (XOR swizzle row&15)

    const int tid  = threadIdx.x;
    const int lane = tid & 63, wave = tid >> 6;
    const int quad = lane >> 4, ln = lane & 15;
    const int r8 = lane >> 3, c8 = lane & 7;      // K staging coords
    const int r4 = lane >> 4, c16 = lane & 15;    // V staging coords

    f16x8 ones;
    #pragma unroll
    for (int j = 0; j < 8; j++) ones[j] = (f16)1.0f;

    for (int pass = 0; pass < 2; pass++) {
        const int qt = pass == 0 ? (31 - p) : p;
        __syncthreads();   // previous pass readers of PQ/Ks/Vs done
        // stage Q tile into the union buffer (plain vector stores)
        #pragma unroll
        for (int i = 0; i < 2; i++) {
            int vi = tid + i * 256;
            int row = vi >> 3, kk = (vi & 7) * 8;
            *(uint4*)&PQ[row][kk] = *(const uint4*)&Qh[(size_t)(qt * 64 + row) * 64 + kk];
        }
        __syncthreads();
        f16x8 qf[2];
        #pragma unroll
        for (int kc = 0; kc < 2; kc++)
            qf[kc] = *(const f16x8*)&PQ[wave * 16 + ln][kc * 32 + quad * 8];

        float m_i[4];
        #pragma unroll
        for (int r = 0; r < 4; r++) m_i[r] = -3e30f;
        f32x4 o[4] = {};
        f32x4 o5 = {};   // l accumulator: PV with all-ones B -> every lane holds row-sum

        const int nkt = (qt + 2) >> 1;    // BK=128 tiles covering (qt+1)*64 keys
        for (int kt = 0; kt < nkt; kt++) {
            __syncthreads();   // previous iteration's Ks/Vs readers done (also guards PQ->P flip)
            #pragma unroll
            for (int i = 0; i < 4; i++) {
                int blk = wave * 4 + i;                 // 0..15
                int krow = blk * 8 + r8;                // 0..127
                gload16(&Ks[blk * 8][0], &Kh[(size_t)(kt * 128 + krow) * 64 + ((c8 ^ r8) * 8)]);
                int vrow = blk * 4 + r4;                // 0..63
                gload16(&Vs[blk * 4][0], &Vh[(size_t)vrow * 2048 + kt * 128 + ((c16 ^ (vrow & 15)) * 8)]);
            }
            __syncthreads();

            // S2 = (Q*log2e) K^T : wave's 16 rows x 128 keys
            f32x4 sf[8] = {};
            #pragma unroll
            for (int kc = 0; kc < 2; kc++)
                #pragma unroll
                for (int ct = 0; ct < 8; ct++) {
                    int krow = ct * 16 + ln;
                    f16x8 kf = *(const f16x8*)&Ks[krow][((kc * 4 + quad) ^ (ln & 7)) * 8];
                    sf[ct] = __builtin_amdgcn_mfma_f32_16x16x32_f16(qf[kc], kf, sf[ct], 0, 0, 0);
                }

            if (kt == nkt - 1) {   // diagonal tile: causal mask (also kills tail over-span)
                #pragma unroll
                for (int ct = 0; ct < 8; ct++) {
                    int jg = kt * 128 + ct * 16 + ln;
                    #pragma unroll
                    for (int r = 0; r < 4; r++) {
                        int ig = qt * 64 + wave * 16 + quad * 4 + r;
                        if (jg > ig) sf[ct][r] = -3e30f;
                    }
                }
            }

            // online softmax (exp2 domain): max-reduce only; sum comes from the ones-MFMA
            #pragma unroll
            for (int r = 0; r < 4; r++) {
                float tm = sf[0][r];
                #pragma unroll
                for (int ct = 1; ct < 8; ct++) tm = fmaxf(tm, sf[ct][r]);
                #pragma unroll
                for (int off = 1; off < 16; off <<= 1) tm = fmaxf(tm, __shfl_xor(tm, off, 64));
                float mnew = fmaxf(m_i[r], tm);
                float a = fast_exp2(m_i[r] - mnew);
                m_i[r] = mnew;
                #pragma unroll
                for (int ct = 0; ct < 8; ct++)
                    sf[ct][r] = fast_exp2(sf[ct][r] - mnew);
                #pragma unroll
                for (int vt = 0; vt < 4; vt++) o[vt][r] *= a;
                o5[r] *= a;
            }

            // P: C-layout -> per-wave-private rows of PQ -> A-layout (no barrier)
            #pragma unroll
            for (int ct = 0; ct < 8; ct++)
                #pragma unroll
                for (int r = 0; r < 4; r++)
                    PQ[wave * 16 + quad * 4 + r][ct * 16 + ln] = (f16)sf[ct][r];

            // O += P V  (A = P[q][key] 16x128, B = V^T[d2][key]); l += P * ones
            #pragma unroll
            for (int kc = 0; kc < 4; kc++) {
                f16x8 pa = *(const f16x8*)&PQ[wave * 16 + ln][kc * 32 + quad * 8];
                #pragma unroll
                for (int vt = 0; vt < 4; vt++) {
                    int vrow = vt * 16 + ln;
                    f16x8 vb = *(const f16x8*)&Vs[vrow][(((kc * 4 + quad) ^ ln) & 15) * 8];
                    o[vt] = __builtin_amdgcn_mfma_f32_16x16x32_f16(pa, vb, o[vt], 0, 0, 0);
                }
                o5 = __builtin_amdgcn_mfma_f32_16x16x32_f16(pa, ones, o5, 0, 0, 0);
            }
        }

        // epilogue: normalize by l (= o5, identical in every lane), scatter to att
        #pragma unroll
        for (int r = 0; r < 4; r++) {
            float inv = 1.0f / o5[r];
            int s2 = qt * 64 + wave * 16 + quad * 4 + r;
            #pragma unroll
            for (int vt = 0; vt < 4; vt++) {
                int d2 = vt * 16 + ln;
                att[((size_t)b * NS + s2) * NDM + h * 64 + d2] = (f16)(o[vt][r] * inv);
            }
        }
    }
}

extern "C" void kernel_launch(void* const* d_in, const int* in_sizes, int n_in,
                              void* d_out, int out_size, void* d_ws, size_t ws_size,
                              hipStream_t stream)
{
    const float* q  = (const float*)d_in[0];
    const float* k  = (const float*)d_in[1];
    const float* v  = (const float*)d_in[2];
    const float* Wq = (const float*)d_in[3];
    const float* Wk = (const float*)d_in[4];
    const float* Wv = (const float*)d_in[5];
    const float* Wp = (const float*)d_in[6];
    float* out = (float*)d_out;

    char* ws = (char*)d_ws;
    const size_t MB = 1024 * 1024;
    f16* qb   = (f16*)(ws + 0 * MB);
    f16* kb   = (f16*)(ws + 8 * MB);
    f16* vb   = (f16*)(ws + 16 * MB);   // reused as Vtg after gemm3 consumes it
    f16* Wqt  = (f16*)(ws + 24 * MB);
    f16* Wkt  = (f16*)(ws + 26 * MB);
    f16* Wvt  = (f16*)(ws + 28 * MB);
    f16* Wpt  = (f16*)(ws + 30 * MB);
    f16* Qp   = (f16*)(ws + 32 * MB);
    f16* Kp   = (f16*)(ws + 40 * MB);
    f16* Vp   = (f16*)(ws + 48 * MB);
    f16* attb = (f16*)(ws + 56 * MB);
    f16* Vtg  = vb;                     // (2,16,64,2048) transposed V heads

    const int M = NB * NS;      // 4096
    const int N = NDM;          // 1024
    const int K = NDM;          // 1024

    prep_kernel<<<dim3(10240), 256, 0, stream>>>(q, k, v, qb, kb, vb,
                                                 Wq, Wk, Wv, Wp, Wqt, Wkt, Wvt, Wpt);
    gemm3_kernel<<<dim3(N / 128, M / 128, 3), 256, 0, stream>>>(qb, kb, vb, Wqt, Wkt, Wvt, Qp, Kp, Vp, M, N, K);
    vtrans_kernel<<<dim3(32, NHEAD, NB), 256, 0, stream>>>(Vp, Vtg);
    attn_kernel<<<dim3(16, NHEAD, NB), 256, 0, stream>>>(Qp, Kp, Vtg, attb);
    gemm_out_kernel<<<dim3(N / 64, M / 128), 256, 0, stream>>>(attb, Wpt, out, M, N, K);
}

// Round 7
// 214.106 us; speedup vs baseline: 1.2689x; 1.1194x over previous
//
#include <hip/hip_runtime.h>
#include <cstdint>
#include <cstddef>

// MultiHeadAttention: B=2,S=2048,D_MODEL=1024,N_HEAD=16, "buggy" reshape:
// head h of batch b is the contiguous block X[b, h*128:(h+1)*128, :] viewed (2048,64).
// R7: XCD-locality scheduling (flat grids + swizzle, block i -> XCD i%8):
//  - attn/vtrans: head (b,h) pinned to XCD (2h+b)&7 -> K/V (2MB/XCD) L2-resident
//  - gemm3: A-row-block pinned to the XCD that later consumes those rows in attn;
//    same-B blocks consecutive -> B ~once/XCD. L3 operand traffic ~384MB -> ~100MB.
//  - gemm_out: A-tiles L2-resident per XCD, Wpt read ~once/XCD.

typedef _Float16 f16;
typedef _Float16 f16x8 __attribute__((ext_vector_type(8)));
typedef float f32x4 __attribute__((ext_vector_type(4)));

#define NB 2
#define NS 2048
#define NDM 1024
#define NHEAD 16

// async global->LDS, 16B per lane; LDS dest = wave-uniform base + lane*16
__device__ __forceinline__ void gload16(void* lds, const void* g) {
    __builtin_amdgcn_global_load_lds(
        (__attribute__((address_space(1))) void*)g,
        (__attribute__((address_space(3))) void*)lds, 16, 0, 0);
}

__device__ __forceinline__ float fast_exp2(float x) {
#if __has_builtin(__builtin_amdgcn_exp2f)
    return __builtin_amdgcn_exp2f(x);
#else
    return __expf(x * 0.69314718055994531f);
#endif
}

// ---------------- fused prep: cast q/k/v -> f16, transpose+cast 4 weight mats ----------------
__global__ __launch_bounds__(256) void prep_kernel(
    const float* __restrict__ q, const float* __restrict__ k, const float* __restrict__ v,
    f16* __restrict__ qb, f16* __restrict__ kb, f16* __restrict__ vb,
    const float* __restrict__ w0, const float* __restrict__ w1,
    const float* __restrict__ w2, const float* __restrict__ w3,
    f16* __restrict__ t0, f16* __restrict__ t1, f16* __restrict__ t2, f16* __restrict__ t3)
{
    __shared__ float tile[32][33];
    const int bx = blockIdx.x, tid = threadIdx.x;
    if (bx < 6144) {
        const int arr = bx >> 11;                 // 0..2
        const float* s = arr == 0 ? q : (arr == 1 ? k : v);
        f16* d        = arr == 0 ? qb : (arr == 1 ? kb : vb);
        int vi = (bx & 2047) * 256 + tid;
        const float4* sp = (const float4*)s;
        float4 a = sp[vi * 2 + 0];
        float4 b = sp[vi * 2 + 1];
        f16x8 h;
        h[0] = (f16)a.x; h[1] = (f16)a.y; h[2] = (f16)a.z; h[3] = (f16)a.w;
        h[4] = (f16)b.x; h[5] = (f16)b.y; h[6] = (f16)b.z; h[7] = (f16)b.w;
        *(f16x8*)(d + (size_t)vi * 8) = h;
    } else {
        const int t = bx - 6144;
        const int mat = t >> 10, tl = t & 1023;
        const float* W; f16* T;
        switch (mat) {
            case 0: W = w0; T = t0; break;
            case 1: W = w1; T = t1; break;
            case 2: W = w2; T = t2; break;
            default: W = w3; T = t3; break;
        }
        const int n = 1024;
        const int tx = tid & 31, ty = tid >> 5;   // (32,8)
        const int c0 = (tl & 31) * 32, r0 = (tl >> 5) * 32;
        #pragma unroll
        for (int i = 0; i < 32; i += 8)
            tile[ty + i][tx] = W[(size_t)(r0 + ty + i) * n + c0 + tx];
        __syncthreads();
        #pragma unroll
        for (int i = 0; i < 32; i += 8)
            T[(size_t)(c0 + ty + i) * n + r0 + tx] = (f16)tile[tx][ty + i];
    }
}

// ---------------- GEMM body  C(MxN) = A(MxK) * Bt(NxK)^T, 128x128 tile, BK=64 ----------------
template <typename CT>
__device__ __forceinline__ void gemm_abt_body(
    const f16* __restrict__ A, const f16* __restrict__ Bt, CT* __restrict__ C,
    int M, int N, int K, int bx, int by, float cscale)
{
    __shared__ f16 As[128][64];
    __shared__ f16 Bs[128][64];
    const int tid  = threadIdx.x;
    const int lane = tid & 63, wave = tid >> 6;
    const int quad = lane >> 4, ln = lane & 15;
    const int wm = wave >> 1, wn = wave & 1;
    const int m0 = by * 128, n0 = bx * 128;
    const int r8 = lane >> 3, c8 = lane & 7;
    const int swz = ((c8 ^ r8) * 8);           // global chunk this lane fetches

    f32x4 acc[4][4] = {};
    for (int k0 = 0; k0 < K; k0 += 64) {
        __syncthreads();
        #pragma unroll
        for (int i = 0; i < 4; i++) {
            int blk = wave * 4 + i;            // 8-row group, 0..15
            int row = blk * 8 + r8;
            gload16(&As[blk * 8][0], &A [(size_t)(m0 + row) * K + k0 + swz]);
            gload16(&Bs[blk * 8][0], &Bt[(size_t)(n0 + row) * K + k0 + swz]);
        }
        __syncthreads();
        #pragma unroll
        for (int kc = 0; kc < 2; kc++) {
            f16x8 af[4], bfr[4];
            #pragma unroll
            for (int mt = 0; mt < 4; mt++)
                af[mt] = *(const f16x8*)&As[wm * 64 + mt * 16 + ln][((kc * 4 + quad) ^ (ln & 7)) * 8];
            #pragma unroll
            for (int nt = 0; nt < 4; nt++)
                bfr[nt] = *(const f16x8*)&Bs[wn * 64 + nt * 16 + ln][((kc * 4 + quad) ^ (ln & 7)) * 8];
            #pragma unroll
            for (int mt = 0; mt < 4; mt++)
                #pragma unroll
                for (int nt = 0; nt < 4; nt++)
                    acc[mt][nt] = __builtin_amdgcn_mfma_f32_16x16x32_f16(af[mt], bfr[nt], acc[mt][nt], 0, 0, 0);
        }
    }
    #pragma unroll
    for (int mt = 0; mt < 4; mt++)
        #pragma unroll
        for (int nt = 0; nt < 4; nt++)
            #pragma unroll
            for (int r = 0; r < 4; r++) {
                int row = m0 + wm * 64 + mt * 16 + quad * 4 + r;
                int col = n0 + wn * 64 + nt * 16 + ln;
                C[(size_t)row * N + col] = (CT)(acc[mt][nt][r] * cscale);
            }
}

// gemm3: flat grid 768. XCD t = (2h+b)&7 where (b,h) = row-block identity (by>>4, by&15)
// -> Q/K/V tiles are produced on the same XCD that attn later reads them from.
// Inner order: idx (A-row) fastest -> consecutive same-XCD blocks share the B tile.
__global__ __launch_bounds__(256) void gemm3_kernel(
    const f16* __restrict__ a0, const f16* __restrict__ a1, const f16* __restrict__ a2,
    const f16* __restrict__ b0, const f16* __restrict__ b1, const f16* __restrict__ b2,
    f16* __restrict__ c0, f16* __restrict__ c1, f16* __restrict__ c2, int M, int N, int K)
{
    const int f = blockIdx.x;          // 0..767
    const int t = f & 7;
    const int r = f >> 3;              // 0..95
    const int idx = r & 3;
    const int r2 = r >> 2;             // 0..23
    const int bx = r2 & 7;
    const int z = r2 >> 3;             // 0..2
    const int by = 16 * (t & 1) + ((t >> 1) & 3) + 4 * idx;

    const f16 *A, *Bt; f16* C; float sc;
    switch (z) {
        case 0: A = a0; Bt = b0; C = c0; sc = 1.4426950408889634f; break;  // Q * log2(e)
        case 1: A = a1; Bt = b1; C = c1; sc = 1.0f; break;
        default: A = a2; Bt = b2; C = c2; sc = 1.0f; break;
    }
    gemm_abt_body<f16>(A, Bt, C, M, N, K, bx, by, sc);
}

// ---------------- out GEMM: 128x64 tiles, flat grid 512 ----------------
// XCD = by&7 -> 4 A-tiles (1MB) resident per XCD; bx outermost -> Wpt tile reused
// by 4 consecutive same-XCD blocks.
__global__ __launch_bounds__(256) void gemm_out_kernel(
    const f16* __restrict__ A, const f16* __restrict__ Bt, float* __restrict__ C,
    int M, int N, int K)
{
    const int f = blockIdx.x;          // 0..511
    const int a7 = f & 7;
    const int r = f >> 3;              // 0..63
    const int idx = r & 3;
    const int bx = r >> 2;             // 0..15
    const int by = a7 + 8 * idx;       // 0..31

    __shared__ f16 As[128][64];   // 16 KB
    __shared__ f16 Bs[64][64];    //  8 KB
    const int tid  = threadIdx.x;
    const int lane = tid & 63, wave = tid >> 6;
    const int quad = lane >> 4, ln = lane & 15;
    const int m0 = by * 128, n0 = bx * 64;
    const int r8 = lane >> 3, c8 = lane & 7;
    const int swz = ((c8 ^ r8) * 8);

    f32x4 acc[2][4] = {};
    for (int k0 = 0; k0 < K; k0 += 64) {
        __syncthreads();
        #pragma unroll
        for (int i = 0; i < 4; i++) {
            int blk = wave * 4 + i;            // 0..15
            gload16(&As[blk * 8][0], &A[(size_t)(m0 + blk * 8 + r8) * K + k0 + swz]);
        }
        #pragma unroll
        for (int i = 0; i < 2; i++) {
            int blk = wave * 2 + i;            // 0..7
            gload16(&Bs[blk * 8][0], &Bt[(size_t)(n0 + blk * 8 + r8) * K + k0 + swz]);
        }
        __syncthreads();
        #pragma unroll
        for (int kc = 0; kc < 2; kc++) {
            f16x8 af[2], bfr[4];
            #pragma unroll
            for (int mt = 0; mt < 2; mt++)
                af[mt] = *(const f16x8*)&As[wave * 32 + mt * 16 + ln][((kc * 4 + quad) ^ (ln & 7)) * 8];
            #pragma unroll
            for (int nt = 0; nt < 4; nt++)
                bfr[nt] = *(const f16x8*)&Bs[nt * 16 + ln][((kc * 4 + quad) ^ (ln & 7)) * 8];
            #pragma unroll
            for (int mt = 0; mt < 2; mt++)
                #pragma unroll
                for (int nt = 0; nt < 4; nt++)
                    acc[mt][nt] = __builtin_amdgcn_mfma_f32_16x16x32_f16(af[mt], bfr[nt], acc[mt][nt], 0, 0, 0);
        }
    }
    #pragma unroll
    for (int mt = 0; mt < 2; mt++)
        #pragma unroll
        for (int nt = 0; nt < 4; nt++)
            #pragma unroll
            for (int r4 = 0; r4 < 4; r4++) {
                int row = m0 + wave * 32 + mt * 16 + quad * 4 + r4;
                int col = n0 + nt * 16 + ln;
                C[(size_t)row * N + col] = acc[mt][nt][r4];
            }
}

// ---------------- global V transpose: per head (2048x64) -> (64x2048) ----------------
// flat grid 1024; head (b,h) pinned to XCD (2h+b)&7 (same as its attn consumers).
__global__ __launch_bounds__(256) void vtrans_kernel(
    const f16* __restrict__ Vp, f16* __restrict__ Vt)
{
    const int f = blockIdx.x;          // 0..1023
    const int t = f & 7;
    const int r = f >> 3;              // 0..127
    const int kt = r & 31;
    const int idxh = r >> 5;           // 0..3
    const int b = t & 1;
    const int h = ((t >> 1) & 3) + 4 * idxh;

    const f16* src = Vp + (size_t)b * (NS * NDM) + (size_t)h * (128 * NDM);  // (2048,64)
    f16* dst = Vt + (size_t)(b * NHEAD + h) * (64 * 2048);

    __shared__ f16 Ls[64][64];
    const int tid = threadIdx.x;
    #pragma unroll
    for (int i = 0; i < 2; i++) {
        int vi = tid + i * 256;
        int key = vi >> 3, c = vi & 7;
        int cs = c ^ ((key >> 3) & 7);
        *(uint4*)&Ls[key][cs * 8] = *(const uint4*)&src[(size_t)(kt * 64 + key) * 64 + c * 8];
    }
    __syncthreads();
    #pragma unroll
    for (int i = 0; i < 2; i++) {
        int vi = tid + i * 256;
        int d2 = vi >> 3, kc = vi & 7;
        int cs = (d2 >> 3) ^ kc;
        f16 tmp[8];
        #pragma unroll
        for (int j = 0; j < 8; j++)
            tmp[j] = Ls[kc * 8 + j][cs * 8 + (d2 & 7)];
        *(uint4*)&dst[(size_t)d2 * 2048 + kt * 64 + kc * 8] = *(uint4*)tmp;
    }
}

// ---------------- flash attention v7 ----------------
// flat grid 512; head (b,h) pinned to XCD (2h+b)&7 -> per-XCD K/V 2MB L2-resident.
// Block pair (p, 31-p): exactly 17 BK=128 iterations. l via ones-MFMA.
__global__ __launch_bounds__(256) void attn_kernel(
    const f16* __restrict__ Qp, const f16* __restrict__ Kp, const f16* __restrict__ Vt,
    f16* __restrict__ att)
{
    const int f = blockIdx.x;          // 0..511
    const int t = f & 7;
    const int r = f >> 3;              // 0..63
    const int p = r & 15;              // pair index
    const int idxh = r >> 4;           // 0..3
    const int b = t & 1;
    const int h = ((t >> 1) & 3) + 4 * idxh;

    const size_t hb = (size_t)b * (NS * NDM) + (size_t)h * (128 * NDM);
    const f16* Qh = Qp + hb;                                    // (2048,64), pre-scaled log2e
    const f16* Kh = Kp + hb;                                    // (2048,64)
    const f16* Vh = Vt + (size_t)(b * NHEAD + h) * (64 * 2048); // (64,2048) transposed

    __shared__ f16 PQ[64][136];      // 17 KB union: Q tile (cols 0..63) -> per-wave P
    __shared__ f16 Ks[128][64];      // 16 KB (XOR swizzle row&7)
    __shared__ f16 Vs[64][128];      // 16 KB Vs[d2][key] (XOR swizzle row&15)

    const int tid  = threadIdx.x;
    const int lane = tid & 63, wave = tid >> 6;
    const int quad = lane >> 4, ln = lane & 15;
    const int r8 = lane >> 3, c8 = lane & 7;      // K staging coords
    const int r4 = lane >> 4, c16 = lane & 15;    // V staging coords

    f16x8 ones;
    #pragma unroll
    for (int j = 0; j < 8; j++) ones[j] = (f16)1.0f;

    for (int pass = 0; pass < 2; pass++) {
        const int qt = pass == 0 ? (31 - p) : p;
        __syncthreads();   // previous pass readers of PQ/Ks/Vs done
        // stage Q tile into the union buffer (plain vector stores)
        #pragma unroll
        for (int i = 0; i < 2; i++) {
            int vi = tid + i * 256;
            int row = vi >> 3, kk = (vi & 7) * 8;
            *(uint4*)&PQ[row][kk] = *(const uint4*)&Qh[(size_t)(qt * 64 + row) * 64 + kk];
        }
        __syncthreads();
        f16x8 qf[2];
        #pragma unroll
        for (int kc = 0; kc < 2; kc++)
            qf[kc] = *(const f16x8*)&PQ[wave * 16 + ln][kc * 32 + quad * 8];

        float m_i[4];
        #pragma unroll
        for (int r2 = 0; r2 < 4; r2++) m_i[r2] = -3e30f;
        f32x4 o[4] = {};
        f32x4 o5 = {};   // l accumulator: PV with all-ones B -> every lane holds row-sum

        const int nkt = (qt + 2) >> 1;    // BK=128 tiles covering (qt+1)*64 keys
        for (int kt = 0; kt < nkt; kt++) {
            __syncthreads();   // previous iteration's Ks/Vs readers done (also guards PQ->P flip)
            #pragma unroll
            for (int i = 0; i < 4; i++) {
                int blk = wave * 4 + i;                 // 0..15
                int krow = blk * 8 + r8;                // 0..127
                gload16(&Ks[blk * 8][0], &Kh[(size_t)(kt * 128 + krow) * 64 + ((c8 ^ r8) * 8)]);
                int vrow = blk * 4 + r4;                // 0..63
                gload16(&Vs[blk * 4][0], &Vh[(size_t)vrow * 2048 + kt * 128 + ((c16 ^ (vrow & 15)) * 8)]);
            }
            __syncthreads();

            // S2 = (Q*log2e) K^T : wave's 16 rows x 128 keys
            f32x4 sf[8] = {};
            #pragma unroll
            for (int kc = 0; kc < 2; kc++)
                #pragma unroll
                for (int ct = 0; ct < 8; ct++) {
                    int krow = ct * 16 + ln;
                    f16x8 kf = *(const f16x8*)&Ks[krow][((kc * 4 + quad) ^ (ln & 7)) * 8];
                    sf[ct] = __builtin_amdgcn_mfma_f32_16x16x32_f16(qf[kc], kf, sf[ct], 0, 0, 0);
                }

            if (kt == nkt - 1) {   // diagonal tile: causal mask (also kills tail over-span)
                #pragma unroll
                for (int ct = 0; ct < 8; ct++) {
                    int jg = kt * 128 + ct * 16 + ln;
                    #pragma unroll
                    for (int r2 = 0; r2 < 4; r2++) {
                        int ig = qt * 64 + wave * 16 + quad * 4 + r2;
                        if (jg > ig) sf[ct][r2] = -3e30f;
                    }
                }
            }

            // online softmax (exp2 domain): max-reduce only; sum comes from the ones-MFMA
            #pragma unroll
            for (int r2 = 0; r2 < 4; r2++) {
                float tm = sf[0][r2];
                #pragma unroll
                for (int ct = 1; ct < 8; ct++) tm = fmaxf(tm, sf[ct][r2]);
                #pragma unroll
                for (int off = 1; off < 16; off <<= 1) tm = fmaxf(tm, __shfl_xor(tm, off, 64));
                float mnew = fmaxf(m_i[r2], tm);
                float a = fast_exp2(m_i[r2] - mnew);
                m_i[r2] = mnew;
                #pragma unroll
                for (int ct = 0; ct < 8; ct++)
                    sf[ct][r2] = fast_exp2(sf[ct][r2] - mnew);
                #pragma unroll
                for (int vt = 0; vt < 4; vt++) o[vt][r2] *= a;
                o5[r2] *= a;
            }

            // P: C-layout -> per-wave-private rows of PQ -> A-layout (no barrier)
            #pragma unroll
            for (int ct = 0; ct < 8; ct++)
                #pragma unroll
                for (int r2 = 0; r2 < 4; r2++)
                    PQ[wave * 16 + quad * 4 + r2][ct * 16 + ln] = (f16)sf[ct][r2];

            // O += P V  (A = P[q][key] 16x128, B = V^T[d2][key]); l += P * ones
            #pragma unroll
            for (int kc = 0; kc < 4; kc++) {
                f16x8 pa = *(const f16x8*)&PQ[wave * 16 + ln][kc * 32 + quad * 8];
                #pragma unroll
                for (int vt = 0; vt < 4; vt++) {
                    int vrow = vt * 16 + ln;
                    f16x8 vb = *(const f16x8*)&Vs[vrow][(((kc * 4 + quad) ^ ln) & 15) * 8];
                    o[vt] = __builtin_amdgcn_mfma_f32_16x16x32_f16(pa, vb, o[vt], 0, 0, 0);
                }
                o5 = __builtin_amdgcn_mfma_f32_16x16x32_f16(pa, ones, o5, 0, 0, 0);
            }
        }

        // epilogue: normalize by l (= o5, identical in every lane), scatter to att
        #pragma unroll
        for (int r2 = 0; r2 < 4; r2++) {
            float inv = 1.0f / o5[r2];
            int s2 = qt * 64 + wave * 16 + quad * 4 + r2;
            #pragma unroll
            for (int vt = 0; vt < 4; vt++) {
                int d2 = vt * 16 + ln;
                att[((size_t)b * NS + s2) * NDM + h * 64 + d2] = (f16)(o[vt][r2] * inv);
            }
        }
    }
}

extern "C" void kernel_launch(void* const* d_in, const int* in_sizes, int n_in,
                              void* d_out, int out_size, void* d_ws, size_t ws_size,
                              hipStream_t stream)
{
    const float* q  = (const float*)d_in[0];
    const float* k  = (const float*)d_in[1];
    const float* v  = (const float*)d_in[2];
    const float* Wq = (const float*)d_in[3];
    const float* Wk = (const float*)d_in[4];
    const float* Wv = (const float*)d_in[5];
    const float* Wp = (const float*)d_in[6];
    float* out = (float*)d_out;

    char* ws = (char*)d_ws;
    const size_t MB = 1024 * 1024;
    f16* qb   = (f16*)(ws + 0 * MB);
    f16* kb   = (f16*)(ws + 8 * MB);
    f16* vb   = (f16*)(ws + 16 * MB);   // reused as Vtg after gemm3 consumes it
    f16* Wqt  = (f16*)(ws + 24 * MB);
    f16* Wkt  = (f16*)(ws + 26 * MB);
    f16* Wvt  = (f16*)(ws + 28 * MB);
    f16* Wpt  = (f16*)(ws + 30 * MB);
    f16* Qp   = (f16*)(ws + 32 * MB);
    f16* Kp   = (f16*)(ws + 40 * MB);
    f16* Vp   = (f16*)(ws + 48 * MB);
    f16* attb = (f16*)(ws + 56 * MB);
    f16* Vtg  = vb;                     // (2,16,64,2048) transposed V heads

    const int M = NB * NS;      // 4096
    const int N = NDM;          // 1024
    const int K = NDM;          // 1024

    prep_kernel<<<dim3(10240), 256, 0, stream>>>(q, k, v, qb, kb, vb,
                                                 Wq, Wk, Wv, Wp, Wqt, Wkt, Wvt, Wpt);
    gemm3_kernel<<<dim3(768), 256, 0, stream>>>(qb, kb, vb, Wqt, Wkt, Wvt, Qp, Kp, Vp, M, N, K);
    vtrans_kernel<<<dim3(1024), 256, 0, stream>>>(Vp, Vtg);
    attn_kernel<<<dim3(512), 256, 0, stream>>>(Qp, Kp, Vtg, attb);
    gemm_out_kernel<<<dim3(512), 256, 0, stream>>>(attb, Wpt, out, M, N, K);
}